// Round 4
// baseline (408.054 us; speedup 1.0000x reference)
//
#include <hip/hip_runtime.h>

// B=65536 rows, F=256 features, T=256 trees, DEPTH=6, C=4 classes.
#define NB 65536
#define NF 256
#define NT 256
#define NC 4
#define NG 8             // tree groups (32 trees each), one per wave
#define TG 32
#define RB 512           // row-blocks = grid size
#define RPB (NB / RB)    // 128 rows per block
#define RPC 8            // rows per chunk
#define NCHUNK (RPB / RPC)  // 16
#define NTHREADS 512     // 8 waves, wave w = tree group w

// Order-preserving float32 -> uint32 (inputs have no NaNs).
__device__ __forceinline__ unsigned int mono32(float v) {
    unsigned int u = __float_as_uint(v);
    return (u & 0x80000000u) ? ~u : (u | 0x80000000u);
}

// Circulant max-reduce over each 16-lane DPP row via v_max_f32 + row_ror
// {1,2,4,8}: after the 4 steps EVERY lane holds the max of its 16-row.
// VALU pipe only.
__device__ __forceinline__ float rowmax16_dpp(float v) {
    int i = __float_as_int(v);
    int r;
    r = __builtin_amdgcn_update_dpp(i, i, 0x121, 0xf, 0xf, true);  // row_ror:1
    i = __float_as_int(fmaxf(__int_as_float(i), __int_as_float(r)));
    r = __builtin_amdgcn_update_dpp(i, i, 0x122, 0xf, 0xf, true);  // row_ror:2
    i = __float_as_int(fmaxf(__int_as_float(i), __int_as_float(r)));
    r = __builtin_amdgcn_update_dpp(i, i, 0x124, 0xf, 0xf, true);  // row_ror:4
    i = __float_as_int(fmaxf(__int_as_float(i), __int_as_float(r)));
    r = __builtin_amdgcn_update_dpp(i, i, 0x128, 0xf, 0xf, true);  // row_ror:8
    i = __float_as_int(fmaxf(__int_as_float(i), __int_as_float(r)));
    return __int_as_float(i);
}

// Lower<->upper half exchange + max, on the VALU pipe (v_permlane32_swap_b32,
// gfx950). Returns max over {lane, lane^32} pair given per-lane value m.
__device__ __forceinline__ float halfswap_max(float m) {
    const int im = __float_as_int(m);
    auto r = __builtin_amdgcn_permlane32_swap(im, im, false, false);
    return fmaxf(__int_as_float(r[0]), __int_as_float(r[1]));
}

// Block = row-range of 128 rows x ALL 256 trees (8 waves = 8 tree groups).
// x staged once per row via global_load_lds (double-buffered prefetch).
// Levels 0..2 in registers; levels 3,4 in LDS transposed [p][tree]
// (2-way banks); level 5 + leaves gathered from L2-hot global.
//
// Lane remap: tree = (lane&15) | ((lane>>1)&16), h = (lane>>4)&1. A wave's
// 32 trees thus occupy one 16-lane DPP row in EACH 32-lane half, so the
// group argmax is rowmax16 (DPP row_ror, VALU) + permlane32_swap (VALU):
// the ENTIRE argmax runs on the VALU pipe -- zero LDS-pipe ops (the LDS
// pipe is this kernel's saturated resource). Ballot bits for the group sit
// in 16-bit fields at s=h*16 and 32+s, in tree order, preserving the
// ffs first-occurrence tie-break. Cross-group combine in double-buffered
// wkey LDS; ONE barrier per chunk.
__global__ __launch_bounds__(NTHREADS, 4) void k_traverse(
    const float* __restrict__ x,
    const int*   __restrict__ root_nodes, const float* __restrict__ root_biases,
    const float* __restrict__ leaf_nodes,
    const int* __restrict__ n1, const float* __restrict__ b1,
    const int* __restrict__ n2, const float* __restrict__ b2,
    const int* __restrict__ n3, const float* __restrict__ b3,
    const int* __restrict__ n4, const float* __restrict__ b4,
    const int* __restrict__ n5, const float* __restrict__ b5,
    float* __restrict__ out_val,   // [B, T, C]
    float* __restrict__ out_arg)   // [B, C]
{
    const int rb = blockIdx.x;

    __shared__ int2  tbl[6144];           // l3 [0,2048): g*256+p*32+lt ; l4 [2048,6144): g*512+p*32+lt
    __shared__ float xr[2][RPC * NF];     // double-buffered 8-row stage (2 x 8 KB)
    __shared__ unsigned long long wkey[2][RPC][NC][NG];  // dbuf argmax keys (4 KB)

    const int tid  = threadIdx.x;
    const int g    = tid >> 6;                      // wave = tree group 0..7
    const int lane = tid & 63;
    const int lt   = (lane & 15) | ((lane >> 1) & 16);  // local tree (bit4 <- lane bit5)
    const int h    = (lane >> 4) & 1;               // row parity (<- lane bit4)
    const int t    = g * TG + lt;                   // global tree
    const int s    = h << 4;                        // ballot field shift

    // ---- per-thread register tables: root + levels 1,2 ----
    const int2 e0   = make_int2(root_nodes[t], __float_as_int(root_biases[t]));
    const int2 e1_0 = make_int2(n1[2 * t],     __float_as_int(b1[2 * t]));
    const int2 e1_1 = make_int2(n1[2 * t + 1], __float_as_int(b1[2 * t + 1]));
    const int2 e2_0 = make_int2(n2[4 * t],     __float_as_int(b2[4 * t]));
    const int2 e2_1 = make_int2(n2[4 * t + 1], __float_as_int(b2[4 * t + 1]));
    const int2 e2_2 = make_int2(n2[4 * t + 2], __float_as_int(b2[4 * t + 2]));
    const int2 e2_3 = make_int2(n2[4 * t + 3], __float_as_int(b2[4 * t + 3]));

    // ---- stage levels 3,4 for ALL groups into LDS, transposed [p][tree] ----
    #pragma unroll
    for (int k = 0; k < 4; ++k) {                      // level 3: 2048 entries (t*8+p)
        const int i = tid + 512 * k;
        const int tt = i >> 3, p = i & 7;
        tbl[((tt >> 5) << 8) + (p << 5) + (tt & 31)] =
            make_int2(n3[i], __float_as_int(b3[i]));
    }
    #pragma unroll
    for (int k = 0; k < 8; ++k) {                      // level 4: 4096 entries (t*16+p)
        const int i = tid + 512 * k;
        const int tt = i >> 4, p = i & 15;
        tbl[2048 + ((tt >> 5) << 9) + (p << 5) + (tt & 31)] =
            make_int2(n4[i], __float_as_int(b4[i]));
    }

    const float4* xg  = (const float4*)x;
    const float4* lf4 = (const float4*)leaf_nodes;
    float4*       ov4 = (float4*)out_val;

    // ---- prologue: stage chunk 0 into buffer 0 ----
    {
        const size_t base4 = (size_t)rb * RPB * (NF / 4);
        __builtin_amdgcn_global_load_lds(
            (const __attribute__((address_space(1))) void*)(xg + base4 + tid),
            (__attribute__((address_space(3))) void*)(((float4*)xr[0]) + tid),
            16, 0, 0);
    }
    __syncthreads();   // tables + chunk-0 stage complete

    int buf = 0;
    for (int ck = 0; ck < NCHUNK; ++ck) {
        const int r0 = rb * RPB + ck * RPC;
        const int kb = ck & 1;        // wkey buffer for this chunk

        // prefetch chunk ck+1 into the other buffer (drained by barrier below)
        if (ck + 1 < NCHUNK) {
            const size_t base4 = (size_t)(r0 + RPC) * (NF / 4);
            __builtin_amdgcn_global_load_lds(
                (const __attribute__((address_space(1))) void*)(xg + base4 + tid),
                (__attribute__((address_space(3))) void*)(((float4*)xr[buf ^ 1]) + tid),
                16, 0, 0);
        }

        // ---- 4 independent chains: rows h, h+2, h+4, h+6 ----
        const float* xb = xr[buf];
        const float* xw[4];
        int p[4];
        #pragma unroll
        for (int j = 0; j < 4; ++j) xw[j] = xb + (h + 2 * j) * NF;

        // root (regs)
        #pragma unroll
        for (int j = 0; j < 4; ++j)
            p[j] = (xw[j][e0.x] >= __int_as_float(e0.y)) ? 1 : 0;
        // level 1 (regs)
        #pragma unroll
        for (int j = 0; j < 4; ++j) {
            const int2 e = p[j] ? e1_1 : e1_0;
            p[j] = 2 * p[j] + (xw[j][e.x] >= __int_as_float(e.y) ? 1 : 0);
        }
        // level 2 (regs, 4-way select)
        #pragma unroll
        for (int j = 0; j < 4; ++j) {
            const int2 a0 = (p[j] & 1) ? e2_1 : e2_0;
            const int2 a1 = (p[j] & 1) ? e2_3 : e2_2;
            const int2 e  = (p[j] & 2) ? a1 : a0;
            p[j] = 2 * p[j] + (xw[j][e.x] >= __int_as_float(e.y) ? 1 : 0);
        }
        // level 3 (LDS, transposed: p in [0,8))
        #pragma unroll
        for (int j = 0; j < 4; ++j) {
            const int2 e = tbl[(g << 8) + (p[j] << 5) + lt];
            p[j] = 2 * p[j] + (xw[j][e.x] >= __int_as_float(e.y) ? 1 : 0);
        }
        // level 4 (LDS, transposed: p in [0,16))
        #pragma unroll
        for (int j = 0; j < 4; ++j) {
            const int2 e = tbl[2048 + (g << 9) + (p[j] << 5) + lt];
            p[j] = 2 * p[j] + (xw[j][e.x] >= __int_as_float(e.y) ? 1 : 0);
        }
        // level 5 (global, L2-hot 32+32 KB tables; p in [0,32))
        #pragma unroll
        for (int j = 0; j < 4; ++j) {
            const int i5 = (t << 5) + p[j];
            const int   nf = n5[i5];
            const float bb = b5[i5];
            p[j] = 2 * p[j] + (xw[j][nf] >= bb ? 1 : 0);
        }

        // leaves (global, L2-hot) + coalesced out_val stores
        float4 leaf[4];
        #pragma unroll
        for (int j = 0; j < 4; ++j)
            leaf[j] = lf4[(size_t)t * 64 + p[j]];
        #pragma unroll
        for (int j = 0; j < 4; ++j)
            ov4[(size_t)(r0 + h + 2 * j) * NT + t] = leaf[j];

        // ---- per-group argmax: DPP rowmax + permlane32_swap (all VALU) ----
        #pragma unroll
        for (int j = 0; j < 4; ++j) {
            const float vcarr[4] = { leaf[j].x, leaf[j].y, leaf[j].z, leaf[j].w };
            unsigned long long kk = 0;
            #pragma unroll
            for (int cls = 0; cls < 4; ++cls) {
                float m = rowmax16_dpp(vcarr[cls]);   // 16-tree max (VALU)
                m = halfswap_max(m);                  // 32-tree max (VALU)
                // every lane now holds its group's max for this class
                const unsigned long long ball = __ballot(vcarr[cls] == m);
                const unsigned int hm =
                    (unsigned int)((ball >> s) & 0xFFFFull) |
                    ((unsigned int)((ball >> (32 + s)) & 0xFFFFull) << 16);
                const int gidx = g * TG + (__ffs(hm) - 1);   // first occurrence
                const unsigned long long kc =
                    ((unsigned long long)mono32(m) << 8) |
                    (unsigned long long)(255 - gidx);
                if (lt == cls) kk = kc;
            }
            if (lt < 4) wkey[kb][h + 2 * j][lt][g] = kk;
        }

        __syncthreads();   // wkey[kb] ready; prefetch drained -> next buf valid

        // ---- cross-group combine: 32 threads finalize 8 rows x 4 classes ----
        // runs concurrently with the next chunk's compute (wkey is dbuf'd)
        if (tid < 32) {
            const int r = tid >> 2, c = tid & 3;
            unsigned long long m = wkey[kb][r][c][0];
            #pragma unroll
            for (int q = 1; q < 8; ++q) {
                const unsigned long long v2 = wkey[kb][r][c][q];
                m = (v2 > m) ? v2 : m;
            }
            out_arg[(size_t)(r0 + r) * NC + c] = (float)(255 - (int)(m & 0xFFull));
        }

        buf ^= 1;
    }
}

extern "C" void kernel_launch(void* const* d_in, const int* in_sizes, int n_in,
                              void* d_out, int out_size, void* d_ws, size_t ws_size,
                              hipStream_t stream) {
    const float* x           = (const float*)d_in[0];
    const int*   root_nodes  = (const int*)  d_in[1];
    const float* root_biases = (const float*)d_in[2];
    const float* leaf_nodes  = (const float*)d_in[3];
    const int*   n1 = (const int*)  d_in[4];
    const float* b1 = (const float*)d_in[5];
    const int*   n2 = (const int*)  d_in[6];
    const float* b2 = (const float*)d_in[7];
    const int*   n3 = (const int*)  d_in[8];
    const float* b3 = (const float*)d_in[9];
    const int*   n4 = (const int*)  d_in[10];
    const float* b4 = (const float*)d_in[11];
    const int*   n5 = (const int*)  d_in[12];
    const float* b5 = (const float*)d_in[13];

    float* out_arg = (float*)d_out;                    // [B, C]
    float* out_val = (float*)d_out + (size_t)NB * NC;  // [B, T, C]

    k_traverse<<<RB, NTHREADS, 0, stream>>>(
        x, root_nodes, root_biases, leaf_nodes,
        n1, b1, n2, b2, n3, b3, n4, b4, n5, b5,
        out_val, out_arg);
}